// Round 14
// baseline (437.338 us; speedup 1.0000x reference)
//
#include <hip/hip_runtime.h>
#include <stdint.h>

typedef unsigned short u16;
typedef _Float16 f16;
typedef __attribute__((ext_vector_type(8))) _Float16 f16x8;
typedef __attribute__((ext_vector_type(4))) float f32x4;

__device__ __forceinline__ float exp2fast(float x) {
  return __builtin_amdgcn_exp2f(x);   // v_exp_f32: 2^x
}

__device__ __forceinline__ f32x4 mfma16(f16x8 a, f16x8 b, f32x4 c) {
  return __builtin_amdgcn_mfma_f32_16x16x32_f16(a, b, c, 0, 0, 0);
}

__device__ __forceinline__ u16 f2h(float f) {
  return __builtin_bit_cast(u16, (f16)f);
}

__device__ __forceinline__ void gld16(const void* g, void* l) {
  __builtin_amdgcn_global_load_lds(
      (const __attribute__((address_space(1))) unsigned int*)g,
      (__attribute__((address_space(3))) unsigned int*)l,
      16, 0, 0);
}

// ---------------- fp32 -> fp16 (plain) ----------------
__global__ __launch_bounds__(256) void cvt_f32_f16(const float* __restrict__ in,
                                                   u16* __restrict__ out, int n4) {
  int stride = gridDim.x * blockDim.x;
  for (int i = blockIdx.x * blockDim.x + threadIdx.x; i < n4; i += stride) {
    float4 v = reinterpret_cast<const float4*>(in)[i];
    ushort4 o;
    o.x = f2h(v.x); o.y = f2h(v.y); o.z = f2h(v.z); o.w = f2h(v.w);
    reinterpret_cast<ushort4*>(out)[i] = o;
  }
}

// batched 4-matrix fp32 -> fp16 (weights), one launch
struct Ptr8 {
  const float *s0, *s1, *s2, *s3;
  u16 *d0, *d1, *d2, *d3;
};
__global__ __launch_bounds__(256) void cvt4_f32_f16(Ptr8 p, int n4) {
  const float* in = (blockIdx.y == 0) ? p.s0 : (blockIdx.y == 1) ? p.s1
                    : (blockIdx.y == 2) ? p.s2 : p.s3;
  u16* out = (blockIdx.y == 0) ? p.d0 : (blockIdx.y == 1) ? p.d1
             : (blockIdx.y == 2) ? p.d2 : p.d3;
  int stride = gridDim.x * blockDim.x;
  for (int i = blockIdx.x * blockDim.x + threadIdx.x; i < n4; i += stride) {
    float4 v = reinterpret_cast<const float4*>(in)[i];
    ushort4 o;
    o.x = f2h(v.x); o.y = f2h(v.y); o.z = f2h(v.z); o.w = f2h(v.w);
    reinterpret_cast<ushort4*>(out)[i] = o;
  }
}

// ============ staging (r8-verified swizzle): R x 64 fp16 tile into LDS [R][64]
// slot = granule ^ (row&7). ITERS*8 rows per wave.
template <int ITERS>
__device__ __forceinline__ void stageR(const u16* __restrict__ M, int r0, int k0,
                                       u16* S, int wid, int lane) {
  const int l8 = lane >> 3;
  const int col = k0 + (((lane & 7) ^ l8) << 3);
#pragma unroll
  for (int it = 0; it < ITERS; ++it) {
    const int rowbase = wid * (ITERS * 8) + it * 8;
    gld16(M + (size_t)(r0 + rowbase + l8) * 1024 + col, S + rowbase * 64);
  }
}

// ============ phase-pipelined GEMM core (T3+T4+T5): BM=256 BN=128 BK=64,
// 8 waves (4Mx2N), 3 LDS buffers, counted vmcnt(6) at tile boundaries,
// 2 phases per K-tile each {stage || ds_read-next || bar || prio+16MFMA+prio || bar}.
// K-tile loads/wave = 6 (A:4, B:2); prefetch depth 2 tiles -> vmcnt(6) counted.
__device__ __forceinline__ void gemm8ph(
    const u16* __restrict__ A, const u16* __restrict__ B,
    int m0, int n0, u16* As, u16* Bs,
    int wid, int lane, f32x4 (&acc)[4][4]) {
  const int wr = wid >> 1, wc = wid & 1;
  const int qd = lane >> 4, lm = lane & 15;
  const int g0 = (qd ^ (lm & 7)) << 3;          // ks=0 granule
  const int g1 = ((4 + qd) ^ (lm & 7)) << 3;    // ks=1 granule
  const int arow = (wr * 64 + lm) * 64;         // + i*1024 per i
  const int brow = (wc * 64 + lm) * 64;         // + j*1024 per j

  // prologue: stage tiles 0,1 into buffers 0,1
  stageR<4>(A, m0, 0,  As,         wid, lane);
  stageR<2>(B, n0, 0,  Bs,         wid, lane);
  stageR<4>(A, m0, 64, As + 16384, wid, lane);
  stageR<2>(B, n0, 64, Bs + 8192,  wid, lane);
  asm volatile("s_waitcnt vmcnt(6)\n\ts_barrier" ::: "memory");  // tile0 landed

  f16x8 a0[4], b0[4], a1[4], b1[4];
#pragma unroll
  for (int i = 0; i < 4; ++i)
    a0[i] = *reinterpret_cast<const f16x8*>(As + arow + i * 1024 + g0);
#pragma unroll
  for (int j = 0; j < 4; ++j)
    b0[j] = *reinterpret_cast<const f16x8*>(Bs + brow + j * 1024 + g0);

  int buf = 0, nb = 2;
  for (int t = 0; t < 16; ++t) {
    const u16* aB = As + buf * 16384;
    const u16* bB = Bs + buf * 8192;
    // ---- phase 0: stage A(t+2) | read ks1 frags | bar | MFMA ks0 | bar ----
    if (t < 14) stageR<4>(A, m0, (t + 2) * 64, As + nb * 16384, wid, lane);
#pragma unroll
    for (int i = 0; i < 4; ++i)
      a1[i] = *reinterpret_cast<const f16x8*>(aB + arow + i * 1024 + g1);
#pragma unroll
    for (int j = 0; j < 4; ++j)
      b1[j] = *reinterpret_cast<const f16x8*>(bB + brow + j * 1024 + g1);
    asm volatile("s_barrier" ::: "memory");
    __builtin_amdgcn_s_setprio(1);
#pragma unroll
    for (int i = 0; i < 4; ++i)
#pragma unroll
      for (int j = 0; j < 4; ++j)
        acc[i][j] = mfma16(a0[i], b0[j], acc[i][j]);
    __builtin_amdgcn_s_setprio(0);
    asm volatile("s_barrier" ::: "memory");
    // ---- phase 1: stage B(t+2) | counted-wait | read next-tile ks0 | MFMA ks1 | bar
    if (t < 14) stageR<2>(B, n0, (t + 2) * 64, Bs + nb * 8192, wid, lane);
    if (t < 15) {
      if (t < 14) asm volatile("s_waitcnt vmcnt(6)\n\ts_barrier" ::: "memory");
      else        asm volatile("s_waitcnt vmcnt(0)\n\ts_barrier" ::: "memory");
      int b2 = buf + 1; if (b2 == 3) b2 = 0;
      const u16* aN = As + b2 * 16384;
      const u16* bN = Bs + b2 * 8192;
#pragma unroll
      for (int i = 0; i < 4; ++i)
        a0[i] = *reinterpret_cast<const f16x8*>(aN + arow + i * 1024 + g0);
#pragma unroll
      for (int j = 0; j < 4; ++j)
        b0[j] = *reinterpret_cast<const f16x8*>(bN + brow + j * 1024 + g0);
    } else {
      asm volatile("s_barrier" ::: "memory");
    }
    __builtin_amdgcn_s_setprio(1);
#pragma unroll
    for (int i = 0; i < 4; ++i)
#pragma unroll
      for (int j = 0; j < 4; ++j)
        acc[i][j] = mfma16(a1[i], b1[j], acc[i][j]);
    __builtin_amdgcn_s_setprio(0);
    asm volatile("s_barrier" ::: "memory");
    ++buf; if (buf == 3) buf = 0;
    ++nb;  if (nb == 3)  nb = 0;
  }
}

// ---------------- unified Q/K/V projection (single-pass fp16) ----------------
//   mat0: Q [b][h][m][j] scaled by 8*log2(e);  mat1: K [b][h][m][j];
//   mat2: Vt [b][h][j][m]
__global__ __launch_bounds__(512, 2) void proj_qkv(
    const u16* __restrict__ xb,
    const u16* __restrict__ wqh, const u16* __restrict__ wkh, const u16* __restrict__ wvh,
    const float* __restrict__ bq, const float* __restrict__ bk, const float* __restrict__ bv,
    u16* __restrict__ Qf, u16* __restrict__ Kf, u16* __restrict__ Vt) {
  const int mat = blockIdx.z;
  const u16* __restrict__ w = (mat == 0) ? wqh : (mat == 1) ? wkh : wvh;
  const float* __restrict__ bias = (mat == 0) ? bq : (mat == 1) ? bk : bv;
  const int m0 = blockIdx.x * 256;
  const int n0 = blockIdx.y * 128;

  __shared__ __align__(16) u16 As[3 * 256 * 64];
  __shared__ __align__(16) u16 Bs[3 * 128 * 64];

  const int tid = threadIdx.x;
  const int lane = tid & 63;
  const int wid = tid >> 6;
  const int wr = wid >> 1, wc = wid & 1;
  const int qd = lane >> 4, lm = lane & 15;

  f32x4 acc[4][4];
#pragma unroll
  for (int i = 0; i < 4; ++i)
#pragma unroll
    for (int j = 0; j < 4; ++j) acc[i][j] = (f32x4){0.f, 0.f, 0.f, 0.f};

  gemm8ph(xb, w, m0, n0, As, Bs, wid, lane, acc);

  const float scale = (mat == 0) ? 11.5415603f : 1.0f;  // 8*log2(e) folded into Q
#pragma unroll
  for (int i = 0; i < 4; ++i) {
#pragma unroll
    for (int r = 0; r < 4; ++r) {
      int R = m0 + wr * 64 + i * 16 + qd * 4 + r;
      int bb = R >> 12, n = R & 4095;
      int cc = n >> 10, s = n & 1023;
      int rb = s & 3, t = s >> 2;
      int m = cc * 256 + t;
#pragma unroll
      for (int j = 0; j < 4; ++j) {
        int e = n0 + wc * 64 + j * 16 + lm;
        int head = e >> 6, jj = e & 63;
        int h = rb * 16 + head;
        float val = (acc[i][j][r] + bias[e]) * scale;
        u16 hv = f2h(val);
        if (mat == 2) {
          Vt[(((size_t)bb * 64 + h) * 64 + jj) * 1024 + m] = hv;
        } else {
          size_t idx = (((size_t)bb * 64 + h) * 1024 + m) * 64 + jj;
          if (mat == 0) Qf[idx] = hv;
          else          Kf[idx] = hv;
        }
      }
    }
  }
}

// swizzled LDS fragment read: row-major [64][64] fp16, 16B-granule XOR swizzle
__device__ __forceinline__ f16x8 lds_frag(const u16* base, int row, int blk) {
  return *reinterpret_cast<const f16x8*>(base + row * 64 + ((blk ^ (row & 7)) << 3));
}

// stage 64x64 fp16 K chunk + V chunk into swizzled LDS via global_load_lds
__device__ __forceinline__ void stage_kv(const u16* __restrict__ Kh,
                                         const u16* __restrict__ Vh, int kc,
                                         u16* KsB, u16* VsB, int wv, int lane) {
  const int l8 = lane >> 3, sl = lane & 7;
  const int rb = wv * 16;
#pragma unroll
  for (int it = 0; it < 2; ++it) {
    int row = rb + it * 8 + l8;
    int gsl = sl ^ l8;  // inverse-swizzled global granule
    gld16(Kh + (size_t)(kc * 64 + row) * 64 + gsl * 8, KsB + (rb + it * 8) * 64);
    gld16(Vh + (size_t)row * 1024 + kc * 64 + gsl * 8, VsB + (rb + it * 8) * 64);
  }
}

// ---------------- flash attention, swapped-QK, in-register P, defer-max ----------
__global__ __launch_bounds__(256) void attn_kernel(
    const u16* __restrict__ Qf, const u16* __restrict__ Kf,
    const u16* __restrict__ Vt, u16* __restrict__ Of) {
  // XCD-bijective swizzle: 8 m-chunks of one bh land on one XCD, adjacent in dispatch
  const int wgid = (blockIdx.x & 7) * 256 + (blockIdx.x >> 3);
  const int bh = wgid >> 3;
  const int m0 = (wgid & 7) * 128;
  const int b = bh >> 6, h = bh & 63;
  const int tid = threadIdx.x, lane = tid & 63, wv = tid >> 6;
  const int qd = lane >> 4, lm = lane & 15;

  __shared__ __align__(16) u16 Ks[2][64 * 64];
  __shared__ __align__(16) u16 Vs[2][64 * 64];

  const size_t hb = (size_t)(b * 64 + h);
  const u16* __restrict__ Qh = Qf + hb * 65536;
  const u16* __restrict__ Kh = Kf + hb * 65536;
  const u16* __restrict__ Vh = Vt + hb * 65536;

  // Q fragments (B-operand: q-row = lm)
  f16x8 qf[2][2];
#pragma unroll
  for (int im = 0; im < 2; ++im)
#pragma unroll
    for (int ks = 0; ks < 2; ++ks)
      qf[im][ks] = *reinterpret_cast<const f16x8*>(
          Qh + (size_t)(m0 + wv * 32 + im * 16 + lm) * 64 + ks * 32 + qd * 8);

  f32x4 oa[2][4];
  float mrow[2] = {-1e30f, -1e30f};
  float lrow[2] = {0.f, 0.f};
#pragma unroll
  for (int im = 0; im < 2; ++im)
#pragma unroll
    for (int jf = 0; jf < 4; ++jf) oa[im][jf] = (f32x4){0.f, 0.f, 0.f, 0.f};

  stage_kv(Kh, Vh, 0, &Ks[0][0], &Vs[0][0], wv, lane);

  for (int kc = 0; kc < 16; ++kc) {
    const int buf = kc & 1;
    __syncthreads();  // drains staging of buf
    if (kc + 1 < 16) stage_kv(Kh, Vh, kc + 1, &Ks[buf ^ 1][0], &Vs[buf ^ 1][0], wv, lane);

    // swapped QK^T: sc[im][nf] rows = k-local (16nf+4qd+r), cols = q (lm)
    f32x4 sc[2][4];
#pragma unroll
    for (int im = 0; im < 2; ++im)
#pragma unroll
      for (int nf = 0; nf < 4; ++nf) sc[im][nf] = (f32x4){0.f, 0.f, 0.f, 0.f};
    __builtin_amdgcn_s_setprio(1);
#pragma unroll
    for (int ks = 0; ks < 2; ++ks) {
      f16x8 kfr[4];
#pragma unroll
      for (int nf = 0; nf < 4; ++nf)
        kfr[nf] = lds_frag(&Ks[buf][0], nf * 16 + lm, ks * 4 + qd);
#pragma unroll
      for (int im = 0; im < 2; ++im)
#pragma unroll
        for (int nf = 0; nf < 4; ++nf)
          sc[im][nf] = mfma16(kfr[nf], qf[im][ks], sc[im][nf]);
    }
    __builtin_amdgcn_s_setprio(0);

    // online softmax (log2 domain), defer-max with THR=8: P bounded by 2^8
    unsigned int pk[2][8];
#pragma unroll
    for (int im = 0; im < 2; ++im) {
      float pm = sc[im][0][0];
#pragma unroll
      for (int nf = 0; nf < 4; ++nf)
#pragma unroll
        for (int r = 0; r < 4; ++r) pm = fmaxf(pm, sc[im][nf][r]);
      pm = fmaxf(pm, __shfl_xor(pm, 16));
      pm = fmaxf(pm, __shfl_xor(pm, 32));
      if (__all(pm <= mrow[im] + 8.0f)) {
        float mn = mrow[im];
        float s = 0.f;
#pragma unroll
        for (int nf = 0; nf < 4; ++nf) {
          float p0 = exp2fast(sc[im][nf][0] - mn);
          float p1 = exp2fast(sc[im][nf][1] - mn);
          float p2 = exp2fast(sc[im][nf][2] - mn);
          float p3 = exp2fast(sc[im][nf][3] - mn);
          s += (p0 + p1) + (p2 + p3);
          pk[im][2 * nf + 0] = __builtin_bit_cast(unsigned int, __builtin_amdgcn_cvt_pkrtz(p0, p1));
          pk[im][2 * nf + 1] = __builtin_bit_cast(unsigned int, __builtin_amdgcn_cvt_pkrtz(p2, p3));
        }
        s += __shfl_xor(s, 16);
        s += __shfl_xor(s, 32);
        lrow[im] += s;
      } else {
        float mn = fmaxf(mrow[im], pm);
        float corr = exp2fast(mrow[im] - mn);
        mrow[im] = mn;
        float s = 0.f;
#pragma unroll
        for (int nf = 0; nf < 4; ++nf) {
          float p0 = exp2fast(sc[im][nf][0] - mn);
          float p1 = exp2fast(sc[im][nf][1] - mn);
          float p2 = exp2fast(sc[im][nf][2] - mn);
          float p3 = exp2fast(sc[im][nf][3] - mn);
          s += (p0 + p1) + (p2 + p3);
          pk[im][2 * nf + 0] = __builtin_bit_cast(unsigned int, __builtin_amdgcn_cvt_pkrtz(p0, p1));
          pk[im][2 * nf + 1] = __builtin_bit_cast(unsigned int, __builtin_amdgcn_cvt_pkrtz(p2, p3));
        }
        s += __shfl_xor(s, 16);
        s += __shfl_xor(s, 32);
        lrow[im] = lrow[im] * corr + s;
#pragma unroll
        for (int r = 0; r < 4; ++r) {
          float cb = __shfl(corr, qd * 4 + r);
#pragma unroll
          for (int jf = 0; jf < 4; ++jf) oa[im][jf][r] *= cb;
        }
      }
    }

    // PV: redistribute P to A-fragment layout via shfl, then MFMA
#pragma unroll
    for (int ks = 0; ks < 2; ++ks) {
      f16x8 vfr[4];
#pragma unroll
      for (int jf = 0; jf < 4; ++jf)
        vfr[jf] = lds_frag(&Vs[buf][0], jf * 16 + lm, ks * 4 + qd);
#pragma unroll
      for (int im = 0; im < 2; ++im) {
        union { unsigned int w[4]; f16x8 hv; } pa;
#pragma unroll
        for (int w = 0; w < 4; ++w) {
          int srcl = (((2 * qd + (w >> 1)) & 3) << 4) + lm;
          unsigned int a0 = __shfl(pk[im][2 * (2 * ks + 0) + (w & 1)], srcl);
          unsigned int a1 = __shfl(pk[im][2 * (2 * ks + 1) + (w & 1)], srcl);
          pa.w[w] = (qd & 2) ? a1 : a0;
        }
        __builtin_amdgcn_s_setprio(1);
#pragma unroll
        for (int jf = 0; jf < 4; ++jf)
          oa[im][jf] = mfma16(pa.hv, vfr[jf], oa[im][jf]);
        __builtin_amdgcn_s_setprio(0);
      }
    }
  }

  // epilogue: normalize, scatter to Of[b][n][f] (fp16)
  const int rb = h >> 4, head = h & 15;
#pragma unroll
  for (int im = 0; im < 2; ++im) {
#pragma unroll
    for (int r = 0; r < 4; ++r) {
      float lb = __shfl(lrow[im], qd * 4 + r);
      float inv = 1.0f / lb;
      int mq = m0 + wv * 32 + im * 16 + qd * 4 + r;
      int c = mq >> 8, t = mq & 255;
      int s = t * 4 + rb;
      int n = c * 1024 + s;
#pragma unroll
      for (int jf = 0; jf < 4; ++jf) {
        int j = jf * 16 + lm;
        int f = head * 64 + j;
        Of[((size_t)b * 4096 + n) * 1024 + f] = f2h(oa[im][jf][r] * inv);
      }
    }
  }
}

// ---------------- output projection GEMM (phase-pipelined core) ----------------
__global__ __launch_bounds__(512, 2) void out_gemm(
    const u16* __restrict__ Of, const u16* __restrict__ woh,
    const float* __restrict__ bo, float* __restrict__ out) {
  const int m0 = blockIdx.x * 256;
  const int n0 = blockIdx.y * 128;

  __shared__ __align__(16) u16 As[3 * 256 * 64];
  __shared__ __align__(16) u16 Bs[3 * 128 * 64];

  const int tid = threadIdx.x;
  const int lane = tid & 63;
  const int wid = tid >> 6;
  const int wr = wid >> 1, wc = wid & 1;
  const int qd = lane >> 4, lm = lane & 15;

  f32x4 acc[4][4];
#pragma unroll
  for (int i = 0; i < 4; ++i)
#pragma unroll
    for (int j = 0; j < 4; ++j) acc[i][j] = (f32x4){0.f, 0.f, 0.f, 0.f};

  gemm8ph(Of, woh, m0, n0, As, Bs, wid, lane, acc);

#pragma unroll
  for (int i = 0; i < 4; ++i) {
#pragma unroll
    for (int r = 0; r < 4; ++r) {
      int R = m0 + wr * 64 + i * 16 + qd * 4 + r;
#pragma unroll
      for (int j = 0; j < 4; ++j) {
        int e = n0 + wc * 64 + j * 16 + lm;
        out[(size_t)R * 1024 + e] = acc[i][j][r] + bo[e];
      }
    }
  }
}

// ---------------- launch ----------------
extern "C" void kernel_launch(void* const* d_in, const int* in_sizes, int n_in,
                              void* d_out, int out_size, void* d_ws, size_t ws_size,
                              hipStream_t stream) {
  const float* x  = (const float*)d_in[0];
  const float* wq = (const float*)d_in[1];
  const float* bq = (const float*)d_in[2];
  const float* wk = (const float*)d_in[3];
  const float* bk = (const float*)d_in[4];
  const float* wv = (const float*)d_in[5];
  const float* bv = (const float*)d_in[6];
  const float* wo = (const float*)d_in[7];
  const float* bo = (const float*)d_in[8];
  float* out = (float*)d_out;

  char* ws = (char*)d_ws;
  u16* xb  = (u16*)(ws + 0);            // 33,554,432 B
  u16* wqh = (u16*)(ws + 33554432);     //  2,097,152 B each
  u16* wkh = (u16*)(ws + 35651584);
  u16* wvh = (u16*)(ws + 37748736);
  u16* woh = (u16*)(ws + 39845888);
  u16* Qfb = (u16*)(ws + 41943040);     // 33,554,432 B  [b][h][m][j] (pre-scaled)
  u16* Kfb = (u16*)(ws + 75497472);     // 33,554,432 B  [b][h][m][j]
  u16* Vtb = (u16*)(ws + 109051904);    // 33,554,432 B  [b][h][j][m]
  u16* Ofb = (u16*)(ws + 142606336);    // 33,554,432 B  [b][n][f]

  cvt_f32_f16<<<4096, 256, 0, stream>>>(x, xb, 16777216 / 4);
  Ptr8 p { wq, wk, wv, wo, wqh, wkh, wvh, woh };
  cvt4_f32_f16<<<dim3(256, 4), 256, 0, stream>>>(p, 1048576 / 4);

  proj_qkv<<<dim3(64, 8, 3), 512, 0, stream>>>(xb, wqh, wkh, wvh, bq, bk, bv,
                                               Qfb, Kfb, Vtb);
  attn_kernel<<<2048, 256, 0, stream>>>(Qfb, Kfb, Vtb, Ofb);
  out_gemm<<<dim3(64, 8), 512, 0, stream>>>(Ofb, woh, bo, out);
}

// Round 15
// 375.671 us; speedup vs baseline: 1.1642x; 1.1642x over previous
//
#include <hip/hip_runtime.h>
#include <stdint.h>

typedef unsigned short u16;
typedef _Float16 f16;
typedef __attribute__((ext_vector_type(8))) _Float16 f16x8;
typedef __attribute__((ext_vector_type(4))) float f32x4;

__device__ __forceinline__ float exp2fast(float x) {
  return __builtin_amdgcn_exp2f(x);   // v_exp_f32: 2^x
}

__device__ __forceinline__ f32x4 mfma16(f16x8 a, f16x8 b, f32x4 c) {
  return __builtin_amdgcn_mfma_f32_16x16x32_f16(a, b, c, 0, 0, 0);
}

__device__ __forceinline__ u16 f2h(float f) {
  return __builtin_bit_cast(u16, (f16)f);
}

__device__ __forceinline__ void gld16(const void* g, void* l) {
  __builtin_amdgcn_global_load_lds(
      (const __attribute__((address_space(1))) unsigned int*)g,
      (__attribute__((address_space(3))) unsigned int*)l,
      16, 0, 0);
}

// ---------------- fp32 -> fp16 (plain) ----------------
__global__ __launch_bounds__(256) void cvt_f32_f16(const float* __restrict__ in,
                                                   u16* __restrict__ out, int n4) {
  int stride = gridDim.x * blockDim.x;
  for (int i = blockIdx.x * blockDim.x + threadIdx.x; i < n4; i += stride) {
    float4 v = reinterpret_cast<const float4*>(in)[i];
    ushort4 o;
    o.x = f2h(v.x); o.y = f2h(v.y); o.z = f2h(v.z); o.w = f2h(v.w);
    reinterpret_cast<ushort4*>(out)[i] = o;
  }
}

// batched 4-matrix fp32 -> fp16 (weights), one launch
struct Ptr8 {
  const float *s0, *s1, *s2, *s3;
  u16 *d0, *d1, *d2, *d3;
};
__global__ __launch_bounds__(256) void cvt4_f32_f16(Ptr8 p, int n4) {
  const float* in = (blockIdx.y == 0) ? p.s0 : (blockIdx.y == 1) ? p.s1
                    : (blockIdx.y == 2) ? p.s2 : p.s3;
  u16* out = (blockIdx.y == 0) ? p.d0 : (blockIdx.y == 1) ? p.d1
             : (blockIdx.y == 2) ? p.d2 : p.d3;
  int stride = gridDim.x * blockDim.x;
  for (int i = blockIdx.x * blockDim.x + threadIdx.x; i < n4; i += stride) {
    float4 v = reinterpret_cast<const float4*>(in)[i];
    ushort4 o;
    o.x = f2h(v.x); o.y = f2h(v.y); o.z = f2h(v.z); o.w = f2h(v.w);
    reinterpret_cast<ushort4*>(out)[i] = o;
  }
}

// ============ GEMM staging (r8-verified swizzle): R x 64 fp16 tile into LDS
// [R][64] with granule XOR swizzle (slot = granule ^ (row&7)).
// ITERS*8 rows per wave; wave covers rows [wid*ITERS*8, (wid+1)*ITERS*8).
template <int ITERS>
__device__ __forceinline__ void stageR(const u16* __restrict__ M, int r0, int k0,
                                       u16* S, int wid, int lane) {
  const int l8 = lane >> 3;
  const int col = k0 + (((lane & 7) ^ l8) << 3);
#pragma unroll
  for (int it = 0; it < ITERS; ++it) {
    const int rowbase = wid * (ITERS * 8) + it * 8;
    gld16(M + (size_t)(r0 + rowbase + l8) * 1024 + col, S + rowbase * 64);
  }
}

// ---------------- unified Q/K/V projection (single-pass fp16) ----------------
// 256x128 tile, 8 waves (512 thr), BK=64, single-buffer LDS 48KB (r13-best).
//   mat0: Q [b][h][m][j] scaled by 8*log2(e);  mat1: K [b][h][m][j];
//   mat2: Vt [b][h][j][m]
__global__ __launch_bounds__(512) void proj_qkv(
    const u16* __restrict__ xb,
    const u16* __restrict__ wqh, const u16* __restrict__ wkh, const u16* __restrict__ wvh,
    const float* __restrict__ bq, const float* __restrict__ bk, const float* __restrict__ bv,
    u16* __restrict__ Qf, u16* __restrict__ Kf, u16* __restrict__ Vt) {
  const int mat = blockIdx.z;
  const u16* __restrict__ w = (mat == 0) ? wqh : (mat == 1) ? wkh : wvh;
  const float* __restrict__ bias = (mat == 0) ? bq : (mat == 1) ? bk : bv;
  const int m0 = blockIdx.x * 256;
  const int n0 = blockIdx.y * 128;

  __shared__ __align__(16) u16 As[256 * 64];
  __shared__ __align__(16) u16 Bs[128 * 64];

  const int tid = threadIdx.x;
  const int lane = tid & 63;
  const int wid = tid >> 6;          // 0..7
  const int wr = wid >> 1;           // 0..3 over M (64-row slots)
  const int wc = wid & 1;            // 0..1 over N (64-col slots)
  const int qd = lane >> 4, lm = lane & 15;

  f32x4 acc[4][4];
#pragma unroll
  for (int i = 0; i < 4; ++i)
#pragma unroll
    for (int j = 0; j < 4; ++j) acc[i][j] = (f32x4){0.f, 0.f, 0.f, 0.f};

  stageR<4>(xb, m0, 0, As, wid, lane);   // 256 rows: 8 waves x 32 rows
  stageR<2>(w, n0, 0, Bs, wid, lane);    // 128 rows: 8 waves x 16 rows

  for (int kt = 0; kt < 16; ++kt) {
    __syncthreads();
#pragma unroll
    for (int ks = 0; ks < 2; ++ks) {
      const int gofs = ((ks * 4 + qd) ^ (lm & 7)) << 3;
      f16x8 af[4], bf[4];
#pragma unroll
      for (int i = 0; i < 4; ++i)
        af[i] = *reinterpret_cast<const f16x8*>(As + (wr * 64 + i * 16 + lm) * 64 + gofs);
#pragma unroll
      for (int j = 0; j < 4; ++j)
        bf[j] = *reinterpret_cast<const f16x8*>(Bs + (wc * 64 + j * 16 + lm) * 64 + gofs);
#pragma unroll
      for (int i = 0; i < 4; ++i)
#pragma unroll
        for (int j = 0; j < 4; ++j)
          acc[i][j] = mfma16(af[i], bf[j], acc[i][j]);
    }
    __syncthreads();
    if (kt + 1 < 16) {
      stageR<4>(xb, m0, (kt + 1) * 64, As, wid, lane);
      stageR<2>(w, n0, (kt + 1) * 64, Bs, wid, lane);
    }
  }

  const float scale = (mat == 0) ? 11.5415603f : 1.0f;  // 8*log2(e) folded into Q
#pragma unroll
  for (int i = 0; i < 4; ++i) {
#pragma unroll
    for (int r = 0; r < 4; ++r) {
      int R = m0 + wr * 64 + i * 16 + qd * 4 + r;
      int bb = R >> 12, n = R & 4095;
      int cc = n >> 10, s = n & 1023;
      int rb = s & 3, t = s >> 2;
      int m = cc * 256 + t;
#pragma unroll
      for (int j = 0; j < 4; ++j) {
        int e = n0 + wc * 64 + j * 16 + lm;
        int head = e >> 6, jj = e & 63;
        int h = rb * 16 + head;
        float val = (acc[i][j][r] + bias[e]) * scale;
        u16 hv = f2h(val);
        if (mat == 2) {
          Vt[(((size_t)bb * 64 + h) * 64 + jj) * 1024 + m] = hv;
        } else {
          size_t idx = (((size_t)bb * 64 + h) * 1024 + m) * 64 + jj;
          if (mat == 0) Qf[idx] = hv;
          else          Kf[idx] = hv;
        }
      }
    }
  }
}

// swizzled LDS fragment read: row-major [64][64] fp16, 16B-granule XOR swizzle
__device__ __forceinline__ f16x8 lds_frag(const u16* base, int row, int blk) {
  return *reinterpret_cast<const f16x8*>(base + row * 64 + ((blk ^ (row & 7)) << 3));
}

// stage 64x64 fp16 K chunk + V chunk into swizzled LDS via global_load_lds
// 8 waves: each wave stages 8 rows of K and 8 rows of V (2 gld16/lane).
__device__ __forceinline__ void stage_kv8(const u16* __restrict__ Kh,
                                          const u16* __restrict__ Vh, int kc,
                                          u16* KsB, u16* VsB, int wv, int lane) {
  const int l8 = lane >> 3, sl = lane & 7;
  const int row = wv * 8 + l8;
  const int gsl = sl ^ l8;  // inverse-swizzled global granule (row&7 == l8)
  gld16(Kh + (size_t)(kc * 64 + row) * 64 + gsl * 8, KsB + (wv * 8) * 64);
  gld16(Vh + (size_t)row * 1024 + kc * 64 + gsl * 8, VsB + (wv * 8) * 64);
}

// ---------------- flash attention: QBLK=256, 8 waves, swapped-QK, defer-max -----
__global__ __launch_bounds__(512) void attn_kernel(
    const u16* __restrict__ Qf, const u16* __restrict__ Kf,
    const u16* __restrict__ Vt, u16* __restrict__ Of) {
  // XCD-bijective swizzle: the 4 m-chunks of one bh land adjacent on one XCD
  const int wgid = (blockIdx.x & 7) * 128 + (blockIdx.x >> 3);
  const int bh = wgid >> 2;
  const int m0 = (wgid & 3) * 256;
  const int b = bh >> 6, h = bh & 63;
  const int tid = threadIdx.x, lane = tid & 63, wv = tid >> 6;  // wv 0..7
  const int qd = lane >> 4, lm = lane & 15;

  __shared__ __align__(16) u16 Ks[2][64 * 64];
  __shared__ __align__(16) u16 Vs[2][64 * 64];

  const size_t hb = (size_t)(b * 64 + h);
  const u16* __restrict__ Qh = Qf + hb * 65536;
  const u16* __restrict__ Kh = Kf + hb * 65536;
  const u16* __restrict__ Vh = Vt + hb * 65536;

  // Q fragments (B-operand: q-row = lm); wave wv owns rows m0+wv*32 .. +31
  f16x8 qf[2][2];
#pragma unroll
  for (int im = 0; im < 2; ++im)
#pragma unroll
    for (int ks = 0; ks < 2; ++ks)
      qf[im][ks] = *reinterpret_cast<const f16x8*>(
          Qh + (size_t)(m0 + wv * 32 + im * 16 + lm) * 64 + ks * 32 + qd * 8);

  f32x4 oa[2][4];
  float mrow[2] = {-1e30f, -1e30f};
  float lrow[2] = {0.f, 0.f};
#pragma unroll
  for (int im = 0; im < 2; ++im)
#pragma unroll
    for (int jf = 0; jf < 4; ++jf) oa[im][jf] = (f32x4){0.f, 0.f, 0.f, 0.f};

  stage_kv8(Kh, Vh, 0, &Ks[0][0], &Vs[0][0], wv, lane);

  for (int kc = 0; kc < 16; ++kc) {
    const int buf = kc & 1;
    __syncthreads();  // drains staging of buf
    if (kc + 1 < 16) stage_kv8(Kh, Vh, kc + 1, &Ks[buf ^ 1][0], &Vs[buf ^ 1][0], wv, lane);

    // swapped QK^T: sc[im][nf] rows = k-local (16nf+4qd+r), cols = q (lm)
    f32x4 sc[2][4];
#pragma unroll
    for (int im = 0; im < 2; ++im)
#pragma unroll
      for (int nf = 0; nf < 4; ++nf) sc[im][nf] = (f32x4){0.f, 0.f, 0.f, 0.f};
    __builtin_amdgcn_s_setprio(1);
#pragma unroll
    for (int ks = 0; ks < 2; ++ks) {
      f16x8 kfr[4];
#pragma unroll
      for (int nf = 0; nf < 4; ++nf)
        kfr[nf] = lds_frag(&Ks[buf][0], nf * 16 + lm, ks * 4 + qd);
#pragma unroll
      for (int im = 0; im < 2; ++im)
#pragma unroll
        for (int nf = 0; nf < 4; ++nf)
          sc[im][nf] = mfma16(kfr[nf], qf[im][ks], sc[im][nf]);
    }
    __builtin_amdgcn_s_setprio(0);

    // online softmax (log2 domain), defer-max with THR=8: P bounded by 2^8
    unsigned int pk[2][8];
#pragma unroll
    for (int im = 0; im < 2; ++im) {
      float pm = sc[im][0][0];
#pragma unroll
      for (int nf = 0; nf < 4; ++nf)
#pragma unroll
        for (int r = 0; r < 4; ++r) pm = fmaxf(pm, sc[im][nf][r]);
      pm = fmaxf(pm, __shfl_xor(pm, 16));
      pm = fmaxf(pm, __shfl_xor(pm, 32));
      if (__all(pm <= mrow[im] + 8.0f)) {
        float mn = mrow[im];
        float s = 0.f;
#pragma unroll
        for (int nf = 0; nf < 4; ++nf) {
          float p0 = exp2fast(sc[im][nf][0] - mn);
          float p1 = exp2fast(sc[im][nf][1] - mn);
          float p2 = exp2fast(sc[im][nf][2] - mn);
          float p3 = exp2fast(sc[im][nf][3] - mn);
          s += (p0 + p1) + (p2 + p3);
          pk[im][2 * nf + 0] = __builtin_bit_cast(unsigned int, __builtin_amdgcn_cvt_pkrtz(p0, p1));
          pk[im][2 * nf + 1] = __builtin_bit_cast(unsigned int, __builtin_amdgcn_cvt_pkrtz(p2, p3));
        }
        s += __shfl_xor(s, 16);
        s += __shfl_xor(s, 32);
        lrow[im] += s;
      } else {
        float mn = fmaxf(mrow[im], pm);
        float corr = exp2fast(mrow[im] - mn);
        mrow[im] = mn;
        float s = 0.f;
#pragma unroll
        for (int nf = 0; nf < 4; ++nf) {
          float p0 = exp2fast(sc[im][nf][0] - mn);
          float p1 = exp2fast(sc[im][nf][1] - mn);
          float p2 = exp2fast(sc[im][nf][2] - mn);
          float p3 = exp2fast(sc[im][nf][3] - mn);
          s += (p0 + p1) + (p2 + p3);
          pk[im][2 * nf + 0] = __builtin_bit_cast(unsigned int, __builtin_amdgcn_cvt_pkrtz(p0, p1));
          pk[im][2 * nf + 1] = __builtin_bit_cast(unsigned int, __builtin_amdgcn_cvt_pkrtz(p2, p3));
        }
        s += __shfl_xor(s, 16);
        s += __shfl_xor(s, 32);
        lrow[im] = lrow[im] * corr + s;
#pragma unroll
        for (int r = 0; r < 4; ++r) {
          float cb = __shfl(corr, qd * 4 + r);
#pragma unroll
          for (int jf = 0; jf < 4; ++jf) oa[im][jf][r] *= cb;
        }
      }
    }

    // PV: redistribute P to A-fragment layout via shfl, then MFMA
#pragma unroll
    for (int ks = 0; ks < 2; ++ks) {
      f16x8 vfr[4];
#pragma unroll
      for (int jf = 0; jf < 4; ++jf)
        vfr[jf] = lds_frag(&Vs[buf][0], jf * 16 + lm, ks * 4 + qd);
#pragma unroll
      for (int im = 0; im < 2; ++im) {
        union { unsigned int w[4]; f16x8 hv; } pa;
#pragma unroll
        for (int w = 0; w < 4; ++w) {
          int srcl = (((2 * qd + (w >> 1)) & 3) << 4) + lm;
          unsigned int a0 = __shfl(pk[im][2 * (2 * ks + 0) + (w & 1)], srcl);
          unsigned int a1 = __shfl(pk[im][2 * (2 * ks + 1) + (w & 1)], srcl);
          pa.w[w] = (qd & 2) ? a1 : a0;
        }
        __builtin_amdgcn_s_setprio(1);
#pragma unroll
        for (int jf = 0; jf < 4; ++jf)
          oa[im][jf] = mfma16(pa.hv, vfr[jf], oa[im][jf]);
        __builtin_amdgcn_s_setprio(0);
      }
    }
  }

  // epilogue: normalize, scatter to Of[b][n][f] (fp16)
  const int rb = h >> 4, head = h & 15;
#pragma unroll
  for (int im = 0; im < 2; ++im) {
#pragma unroll
    for (int r = 0; r < 4; ++r) {
      float lb = __shfl(lrow[im], qd * 4 + r);
      float inv = 1.0f / lb;
      int mq = m0 + wv * 32 + im * 16 + qd * 4 + r;
      int c = mq >> 8, t = mq & 255;
      int s = t * 4 + rb;
      int n = c * 1024 + s;
#pragma unroll
      for (int jf = 0; jf < 4; ++jf) {
        int j = jf * 16 + lm;
        int f = head * 64 + j;
        Of[((size_t)b * 4096 + n) * 1024 + f] = f2h(oa[im][jf][r] * inv);
      }
    }
  }
}

// ---------------- output projection GEMM (256x128 tile, 8 waves, r13-best) -------
__global__ __launch_bounds__(512) void out_gemm(
    const u16* __restrict__ Of, const u16* __restrict__ woh,
    const float* __restrict__ bo, float* __restrict__ out) {
  const int m0 = blockIdx.x * 256;
  const int n0 = blockIdx.y * 128;

  __shared__ __align__(16) u16 As[256 * 64];
  __shared__ __align__(16) u16 Bs[128 * 64];

  const int tid = threadIdx.x;
  const int lane = tid & 63;
  const int wid = tid >> 6;
  const int wr = wid >> 1, wc = wid & 1;
  const int qd = lane >> 4, lm = lane & 15;

  f32x4 acc[4][4];
#pragma unroll
  for (int i = 0; i < 4; ++i)
#pragma unroll
    for (int j = 0; j < 4; ++j) acc[i][j] = (f32x4){0.f, 0.f, 0.f, 0.f};

  stageR<4>(Of, m0, 0, As, wid, lane);
  stageR<2>(woh, n0, 0, Bs, wid, lane);

  for (int kt = 0; kt < 16; ++kt) {
    __syncthreads();
#pragma unroll
    for (int ks = 0; ks < 2; ++ks) {
      const int gofs = ((ks * 4 + qd) ^ (lm & 7)) << 3;
      f16x8 af[4], bf[4];
#pragma unroll
      for (int i = 0; i < 4; ++i)
        af[i] = *reinterpret_cast<const f16x8*>(As + (wr * 64 + i * 16 + lm) * 64 + gofs);
#pragma unroll
      for (int j = 0; j < 4; ++j)
        bf[j] = *reinterpret_cast<const f16x8*>(Bs + (wc * 64 + j * 16 + lm) * 64 + gofs);
#pragma unroll
      for (int i = 0; i < 4; ++i)
#pragma unroll
        for (int j = 0; j < 4; ++j)
          acc[i][j] = mfma16(af[i], bf[j], acc[i][j]);
    }
    __syncthreads();
    if (kt + 1 < 16) {
      stageR<4>(Of, m0, (kt + 1) * 64, As, wid, lane);
      stageR<2>(woh, n0, (kt + 1) * 64, Bs, wid, lane);
    }
  }

#pragma unroll
  for (int i = 0; i < 4; ++i) {
#pragma unroll
    for (int r = 0; r < 4; ++r) {
      int R = m0 + wr * 64 + i * 16 + qd * 4 + r;
#pragma unroll
      for (int j = 0; j < 4; ++j) {
        int e = n0 + wc * 64 + j * 16 + lm;
        out[(size_t)R * 1024 + e] = acc[i][j][r] + bo[e];
      }
    }
  }
}

// ---------------- launch ----------------
extern "C" void kernel_launch(void* const* d_in, const int* in_sizes, int n_in,
                              void* d_out, int out_size, void* d_ws, size_t ws_size,
                              hipStream_t stream) {
  const float* x  = (const float*)d_in[0];
  const float* wq = (const float*)d_in[1];
  const float* bq = (const float*)d_in[2];
  const float* wk = (const float*)d_in[3];
  const float* bk = (const float*)d_in[4];
  const float* wv = (const float*)d_in[5];
  const float* bv = (const float*)d_in[6];
  const float* wo = (const float*)d_in[7];
  const float* bo = (const float*)d_in[8];
  float* out = (float*)d_out;

  char* ws = (char*)d_ws;
  u16* xb  = (u16*)(ws + 0);            // 33,554,432 B
  u16* wqh = (u16*)(ws + 33554432);     //  2,097,152 B each
  u16* wkh = (u16*)(ws + 35651584);
  u16* wvh = (u16*)(ws + 37748736);
  u16* woh = (u16*)(ws + 39845888);
  u16* Qfb = (u16*)(ws + 41943040);     // 33,554,432 B  [b][h][m][j] (pre-scaled)
  u16* Kfb = (u16*)(ws + 75497472);     // 33,554,432 B  [b][h][m][j]
  u16* Vtb = (u16*)(ws + 109051904);    // 33,554,432 B  [b][h][j][m]
  u16* Ofb = (u16*)(ws + 142606336);    // 33,554,432 B  [b][n][f]

  cvt_f32_f16<<<4096, 256, 0, stream>>>(x, xb, 16777216 / 4);
  Ptr8 p { wq, wk, wv, wo, wqh, wkh, wvh, woh };
  cvt4_f32_f16<<<dim3(256, 4), 256, 0, stream>>>(p, 1048576 / 4);

  proj_qkv<<<dim3(64, 8, 3), 512, 0, stream>>>(xb, wqh, wkh, wvh, bq, bk, bv,
                                               Qfb, Kfb, Vtb);
  attn_kernel<<<1024, 512, 0, stream>>>(Qfb, Kfb, Vtb, Ofb);
  out_gemm<<<dim3(64, 8), 512, 0, stream>>>(Ofb, woh, bo, out);
}

// Round 16
// 370.705 us; speedup vs baseline: 1.1797x; 1.0134x over previous
//
#include <hip/hip_runtime.h>
#include <stdint.h>

typedef unsigned short u16;
typedef _Float16 f16;
typedef __attribute__((ext_vector_type(8))) _Float16 f16x8;
typedef __attribute__((ext_vector_type(4))) float f32x4;

__device__ __forceinline__ float exp2fast(float x) {
  return __builtin_amdgcn_exp2f(x);   // v_exp_f32: 2^x
}

__device__ __forceinline__ f32x4 mfma16(f16x8 a, f16x8 b, f32x4 c) {
  return __builtin_amdgcn_mfma_f32_16x16x32_f16(a, b, c, 0, 0, 0);
}

__device__ __forceinline__ u16 f2h(float f) {
  return __builtin_bit_cast(u16, (f16)f);
}

__device__ __forceinline__ void gld16(const void* g, void* l) {
  __builtin_amdgcn_global_load_lds(
      (const __attribute__((address_space(1))) unsigned int*)g,
      (__attribute__((address_space(3))) unsigned int*)l,
      16, 0, 0);
}

// ---------------- fp32 -> fp16 (plain) ----------------
__global__ __launch_bounds__(256) void cvt_f32_f16(const float* __restrict__ in,
                                                   u16* __restrict__ out, int n4) {
  int stride = gridDim.x * blockDim.x;
  for (int i = blockIdx.x * blockDim.x + threadIdx.x; i < n4; i += stride) {
    float4 v = reinterpret_cast<const float4*>(in)[i];
    ushort4 o;
    o.x = f2h(v.x); o.y = f2h(v.y); o.z = f2h(v.z); o.w = f2h(v.w);
    reinterpret_cast<ushort4*>(out)[i] = o;
  }
}

// batched 4-matrix fp32 -> fp16 (weights), one launch
struct Ptr8 {
  const float *s0, *s1, *s2, *s3;
  u16 *d0, *d1, *d2, *d3;
};
__global__ __launch_bounds__(256) void cvt4_f32_f16(Ptr8 p, int n4) {
  const float* in = (blockIdx.y == 0) ? p.s0 : (blockIdx.y == 1) ? p.s1
                    : (blockIdx.y == 2) ? p.s2 : p.s3;
  u16* out = (blockIdx.y == 0) ? p.d0 : (blockIdx.y == 1) ? p.d1
             : (blockIdx.y == 2) ? p.d2 : p.d3;
  int stride = gridDim.x * blockDim.x;
  for (int i = blockIdx.x * blockDim.x + threadIdx.x; i < n4; i += stride) {
    float4 v = reinterpret_cast<const float4*>(in)[i];
    ushort4 o;
    o.x = f2h(v.x); o.y = f2h(v.y); o.z = f2h(v.z); o.w = f2h(v.w);
    reinterpret_cast<ushort4*>(out)[i] = o;
  }
}

// ============ GEMM staging (r8-verified swizzle): R x 64 fp16 tile into LDS
// [R][64] with granule XOR swizzle (slot = granule ^ (row&7)).
// ITERS*8 rows per wave; wave covers rows [wid*ITERS*8, (wid+1)*ITERS*8).
template <int ITERS>
__device__ __forceinline__ void stageR(const u16* __restrict__ M, int r0, int k0,
                                       u16* S, int wid, int lane) {
  const int l8 = lane >> 3;
  const int col = k0 + (((lane & 7) ^ l8) << 3);
#pragma unroll
  for (int it = 0; it < ITERS; ++it) {
    const int rowbase = wid * (ITERS * 8) + it * 8;
    gld16(M + (size_t)(r0 + rowbase + l8) * 1024 + col, S + rowbase * 64);
  }
}

// ---------------- unified Q/K/V projection (single-pass fp16) ----------------
// 256x128 tile, 8 waves (512 thr), BK=64, single-buffer LDS 48KB.
// STAGE-EARLY schedule: {bar; read ALL frags; bar; stage(kt+1); MFMA} — the
// MFMA block now sits between stage-issue and the next vmcnt(0) drain,
// hiding the load flight (r13/r15 issued stage right before the drain: 0 overlap).
//   mat0: Q [b][h][m][j] scaled by 8*log2(e);  mat1: K [b][h][m][j];
//   mat2: Vt [b][h][j][m]
__global__ __launch_bounds__(512) void proj_qkv(
    const u16* __restrict__ xb,
    const u16* __restrict__ wqh, const u16* __restrict__ wkh, const u16* __restrict__ wvh,
    const float* __restrict__ bq, const float* __restrict__ bk, const float* __restrict__ bv,
    u16* __restrict__ Qf, u16* __restrict__ Kf, u16* __restrict__ Vt) {
  const int mat = blockIdx.z;
  const u16* __restrict__ w = (mat == 0) ? wqh : (mat == 1) ? wkh : wvh;
  const float* __restrict__ bias = (mat == 0) ? bq : (mat == 1) ? bk : bv;
  const int m0 = blockIdx.x * 256;
  const int n0 = blockIdx.y * 128;

  __shared__ __align__(16) u16 As[256 * 64];
  __shared__ __align__(16) u16 Bs[128 * 64];

  const int tid = threadIdx.x;
  const int lane = tid & 63;
  const int wid = tid >> 6;          // 0..7
  const int wr = wid >> 1;           // 0..3 over M (64-row slots)
  const int wc = wid & 1;            // 0..1 over N (64-col slots)
  const int qd = lane >> 4, lm = lane & 15;

  f32x4 acc[4][4];
#pragma unroll
  for (int i = 0; i < 4; ++i)
#pragma unroll
    for (int j = 0; j < 4; ++j) acc[i][j] = (f32x4){0.f, 0.f, 0.f, 0.f};

  stageR<4>(xb, m0, 0, As, wid, lane);   // 256 rows: 8 waves x 32 rows
  stageR<2>(w, n0, 0, Bs, wid, lane);    // 128 rows: 8 waves x 16 rows

  for (int kt = 0; kt < 16; ++kt) {
    __syncthreads();                      // tile kt landed (vmcnt0 drain)
    f16x8 af[2][4], bf[2][4];
#pragma unroll
    for (int ks = 0; ks < 2; ++ks) {
      const int gofs = ((ks * 4 + qd) ^ (lm & 7)) << 3;
#pragma unroll
      for (int i = 0; i < 4; ++i)
        af[ks][i] = *reinterpret_cast<const f16x8*>(As + (wr * 64 + i * 16 + lm) * 64 + gofs);
#pragma unroll
      for (int j = 0; j < 4; ++j)
        bf[ks][j] = *reinterpret_cast<const f16x8*>(Bs + (wc * 64 + j * 16 + lm) * 64 + gofs);
    }
    __syncthreads();                      // all waves done reading tile kt (WAR-safe)
    if (kt + 1 < 16) {
      stageR<4>(xb, m0, (kt + 1) * 64, As, wid, lane);
      stageR<2>(w, n0, (kt + 1) * 64, Bs, wid, lane);
    }
    __builtin_amdgcn_sched_barrier(0);    // keep stage-issue ahead of the MFMA block
#pragma unroll
    for (int ks = 0; ks < 2; ++ks)
#pragma unroll
      for (int i = 0; i < 4; ++i)
#pragma unroll
        for (int j = 0; j < 4; ++j)
          acc[i][j] = mfma16(af[ks][i], bf[ks][j], acc[i][j]);
  }

  const float scale = (mat == 0) ? 11.5415603f : 1.0f;  // 8*log2(e) folded into Q
#pragma unroll
  for (int i = 0; i < 4; ++i) {
#pragma unroll
    for (int r = 0; r < 4; ++r) {
      int R = m0 + wr * 64 + i * 16 + qd * 4 + r;
      int bb = R >> 12, n = R & 4095;
      int cc = n >> 10, s = n & 1023;
      int rb = s & 3, t = s >> 2;
      int m = cc * 256 + t;
#pragma unroll
      for (int j = 0; j < 4; ++j) {
        int e = n0 + wc * 64 + j * 16 + lm;
        int head = e >> 6, jj = e & 63;
        int h = rb * 16 + head;
        float val = (acc[i][j][r] + bias[e]) * scale;
        u16 hv = f2h(val);
        if (mat == 2) {
          Vt[(((size_t)bb * 64 + h) * 64 + jj) * 1024 + m] = hv;
        } else {
          size_t idx = (((size_t)bb * 64 + h) * 1024 + m) * 64 + jj;
          if (mat == 0) Qf[idx] = hv;
          else          Kf[idx] = hv;
        }
      }
    }
  }
}

// swizzled LDS fragment read: row-major [64][64] fp16, 16B-granule XOR swizzle
__device__ __forceinline__ f16x8 lds_frag(const u16* base, int row, int blk) {
  return *reinterpret_cast<const f16x8*>(base + row * 64 + ((blk ^ (row & 7)) << 3));
}

// stage 64x64 fp16 K chunk + V chunk into swizzled LDS via global_load_lds
// 8 waves: each wave stages 8 rows of K and 8 rows of V (2 gld16/lane).
__device__ __forceinline__ void stage_kv8(const u16* __restrict__ Kh,
                                          const u16* __restrict__ Vh, int kc,
                                          u16* KsB, u16* VsB, int wv, int lane) {
  const int l8 = lane >> 3, sl = lane & 7;
  const int row = wv * 8 + l8;
  const int gsl = sl ^ l8;  // inverse-swizzled global granule (row&7 == l8)
  gld16(Kh + (size_t)(kc * 64 + row) * 64 + gsl * 8, KsB + (wv * 8) * 64);
  gld16(Vh + (size_t)row * 1024 + kc * 64 + gsl * 8, VsB + (wv * 8) * 64);
}

// ---------------- flash attention: QBLK=256, 8 waves, swapped-QK, defer-max -----
__global__ __launch_bounds__(512) void attn_kernel(
    const u16* __restrict__ Qf, const u16* __restrict__ Kf,
    const u16* __restrict__ Vt, u16* __restrict__ Of) {
  // XCD-bijective swizzle: the 4 m-chunks of one bh land adjacent on one XCD
  const int wgid = (blockIdx.x & 7) * 128 + (blockIdx.x >> 3);
  const int bh = wgid >> 2;
  const int m0 = (wgid & 3) * 256;
  const int b = bh >> 6, h = bh & 63;
  const int tid = threadIdx.x, lane = tid & 63, wv = tid >> 6;  // wv 0..7
  const int qd = lane >> 4, lm = lane & 15;

  __shared__ __align__(16) u16 Ks[2][64 * 64];
  __shared__ __align__(16) u16 Vs[2][64 * 64];

  const size_t hb = (size_t)(b * 64 + h);
  const u16* __restrict__ Qh = Qf + hb * 65536;
  const u16* __restrict__ Kh = Kf + hb * 65536;
  const u16* __restrict__ Vh = Vt + hb * 65536;

  // Q fragments (B-operand: q-row = lm); wave wv owns rows m0+wv*32 .. +31
  f16x8 qf[2][2];
#pragma unroll
  for (int im = 0; im < 2; ++im)
#pragma unroll
    for (int ks = 0; ks < 2; ++ks)
      qf[im][ks] = *reinterpret_cast<const f16x8*>(
          Qh + (size_t)(m0 + wv * 32 + im * 16 + lm) * 64 + ks * 32 + qd * 8);

  f32x4 oa[2][4];
  float mrow[2] = {-1e30f, -1e30f};
  float lrow[2] = {0.f, 0.f};
#pragma unroll
  for (int im = 0; im < 2; ++im)
#pragma unroll
    for (int jf = 0; jf < 4; ++jf) oa[im][jf] = (f32x4){0.f, 0.f, 0.f, 0.f};

  stage_kv8(Kh, Vh, 0, &Ks[0][0], &Vs[0][0], wv, lane);

  for (int kc = 0; kc < 16; ++kc) {
    const int buf = kc & 1;
    __syncthreads();  // drains staging of buf
    if (kc + 1 < 16) stage_kv8(Kh, Vh, kc + 1, &Ks[buf ^ 1][0], &Vs[buf ^ 1][0], wv, lane);

    // swapped QK^T: sc[im][nf] rows = k-local (16nf+4qd+r), cols = q (lm)
    f32x4 sc[2][4];
#pragma unroll
    for (int im = 0; im < 2; ++im)
#pragma unroll
      for (int nf = 0; nf < 4; ++nf) sc[im][nf] = (f32x4){0.f, 0.f, 0.f, 0.f};
    __builtin_amdgcn_s_setprio(1);
#pragma unroll
    for (int ks = 0; ks < 2; ++ks) {
      f16x8 kfr[4];
#pragma unroll
      for (int nf = 0; nf < 4; ++nf)
        kfr[nf] = lds_frag(&Ks[buf][0], nf * 16 + lm, ks * 4 + qd);
#pragma unroll
      for (int im = 0; im < 2; ++im)
#pragma unroll
        for (int nf = 0; nf < 4; ++nf)
          sc[im][nf] = mfma16(kfr[nf], qf[im][ks], sc[im][nf]);
    }
    __builtin_amdgcn_s_setprio(0);

    // online softmax (log2 domain), defer-max with THR=8: P bounded by 2^8
    unsigned int pk[2][8];
#pragma unroll
    for (int im = 0; im < 2; ++im) {
      float pm = sc[im][0][0];
#pragma unroll
      for (int nf = 0; nf < 4; ++nf)
#pragma unroll
        for (int r = 0; r < 4; ++r) pm = fmaxf(pm, sc[im][nf][r]);
      pm = fmaxf(pm, __shfl_xor(pm, 16));
      pm = fmaxf(pm, __shfl_xor(pm, 32));
      if (__all(pm <= mrow[im] + 8.0f)) {
        float mn = mrow[im];
        float s = 0.f;
#pragma unroll
        for (int nf = 0; nf < 4; ++nf) {
          float p0 = exp2fast(sc[im][nf][0] - mn);
          float p1 = exp2fast(sc[im][nf][1] - mn);
          float p2 = exp2fast(sc[im][nf][2] - mn);
          float p3 = exp2fast(sc[im][nf][3] - mn);
          s += (p0 + p1) + (p2 + p3);
          pk[im][2 * nf + 0] = __builtin_bit_cast(unsigned int, __builtin_amdgcn_cvt_pkrtz(p0, p1));
          pk[im][2 * nf + 1] = __builtin_bit_cast(unsigned int, __builtin_amdgcn_cvt_pkrtz(p2, p3));
        }
        s += __shfl_xor(s, 16);
        s += __shfl_xor(s, 32);
        lrow[im] += s;
      } else {
        float mn = fmaxf(mrow[im], pm);
        float corr = exp2fast(mrow[im] - mn);
        mrow[im] = mn;
        float s = 0.f;
#pragma unroll
        for (int nf = 0; nf < 4; ++nf) {
          float p0 = exp2fast(sc[im][nf][0] - mn);
          float p1 = exp2fast(sc[im][nf][1] - mn);
          float p2 = exp2fast(sc[im][nf][2] - mn);
          float p3 = exp2fast(sc[im][nf][3] - mn);
          s += (p0 + p1) + (p2 + p3);
          pk[im][2 * nf + 0] = __builtin_bit_cast(unsigned int, __builtin_amdgcn_cvt_pkrtz(p0, p1));
          pk[im][2 * nf + 1] = __builtin_bit_cast(unsigned int, __builtin_amdgcn_cvt_pkrtz(p2, p3));
        }
        s += __shfl_xor(s, 16);
        s += __shfl_xor(s, 32);
        lrow[im] = lrow[im] * corr + s;
#pragma unroll
        for (int r = 0; r < 4; ++r) {
          float cb = __shfl(corr, qd * 4 + r);
#pragma unroll
          for (int jf = 0; jf < 4; ++jf) oa[im][jf][r] *= cb;
        }
      }
    }

    // PV: redistribute P to A-fragment layout via shfl, then MFMA
#pragma unroll
    for (int ks = 0; ks < 2; ++ks) {
      f16x8 vfr[4];
#pragma unroll
      for (int jf = 0; jf < 4; ++jf)
        vfr[jf] = lds_frag(&Vs[buf][0], jf * 16 + lm, ks * 4 + qd);
#pragma unroll
      for (int im = 0; im < 2; ++im) {
        union { unsigned int w[4]; f16x8 hv; } pa;
#pragma unroll
        for (int w = 0; w < 4; ++w) {
          int srcl = (((2 * qd + (w >> 1)) & 3) << 4) + lm;
          unsigned int a0 = __shfl(pk[im][2 * (2 * ks + 0) + (w & 1)], srcl);
          unsigned int a1 = __shfl(pk[im][2 * (2 * ks + 1) + (w & 1)], srcl);
          pa.w[w] = (qd & 2) ? a1 : a0;
        }
        __builtin_amdgcn_s_setprio(1);
#pragma unroll
        for (int jf = 0; jf < 4; ++jf)
          oa[im][jf] = mfma16(pa.hv, vfr[jf], oa[im][jf]);
        __builtin_amdgcn_s_setprio(0);
      }
    }
  }

  // epilogue: normalize, scatter to Of[b][n][f] (fp16)
  const int rb = h >> 4, head = h & 15;
#pragma unroll
  for (int im = 0; im < 2; ++im) {
#pragma unroll
    for (int r = 0; r < 4; ++r) {
      float lb = __shfl(lrow[im], qd * 4 + r);
      float inv = 1.0f / lb;
      int mq = m0 + wv * 32 + im * 16 + qd * 4 + r;
      int c = mq >> 8, t = mq & 255;
      int s = t * 4 + rb;
      int n = c * 1024 + s;
#pragma unroll
      for (int jf = 0; jf < 4; ++jf) {
        int j = jf * 16 + lm;
        int f = head * 64 + j;
        Of[((size_t)b * 4096 + n) * 1024 + f] = f2h(oa[im][jf][r] * inv);
      }
    }
  }
}

// ---------------- output projection GEMM (stage-early schedule) ----------------
__global__ __launch_bounds__(512) void out_gemm(
    const u16* __restrict__ Of, const u16* __restrict__ woh,
    const float* __restrict__ bo, float* __restrict__ out) {
  const int m0 = blockIdx.x * 256;
  const int n0 = blockIdx.y * 128;

  __shared__ __align__(16) u16 As[256 * 64];
  __shared__ __align__(16) u16 Bs[128 * 64];

  const int tid = threadIdx.x;
  const int lane = tid & 63;
  const int wid = tid >> 6;
  const int wr = wid >> 1, wc = wid & 1;
  const int qd = lane >> 4, lm = lane & 15;

  f32x4 acc[4][4];
#pragma unroll
  for (int i = 0; i < 4; ++i)
#pragma unroll
    for (int j = 0; j < 4; ++j) acc[i][j] = (f32x4){0.f, 0.f, 0.f, 0.f};

  stageR<4>(Of, m0, 0, As, wid, lane);
  stageR<2>(woh, n0, 0, Bs, wid, lane);

  for (int kt = 0; kt < 16; ++kt) {
    __syncthreads();
    f16x8 af[2][4], bf[2][4];
#pragma unroll
    for (int ks = 0; ks < 2; ++ks) {
      const int gofs = ((ks * 4 + qd) ^ (lm & 7)) << 3;
#pragma unroll
      for (int i = 0; i < 4; ++i)
        af[ks][i] = *reinterpret_cast<const f16x8*>(As + (wr * 64 + i * 16 + lm) * 64 + gofs);
#pragma unroll
      for (int j = 0; j < 4; ++j)
        bf[ks][j] = *reinterpret_cast<const f16x8*>(Bs + (wc * 64 + j * 16 + lm) * 64 + gofs);
    }
    __syncthreads();
    if (kt + 1 < 16) {
      stageR<4>(Of, m0, (kt + 1) * 64, As, wid, lane);
      stageR<2>(woh, n0, (kt + 1) * 64, Bs, wid, lane);
    }
    __builtin_amdgcn_sched_barrier(0);
#pragma unroll
    for (int ks = 0; ks < 2; ++ks)
#pragma unroll
      for (int i = 0; i < 4; ++i)
#pragma unroll
        for (int j = 0; j < 4; ++j)
          acc[i][j] = mfma16(af[ks][i], bf[ks][j], acc[i][j]);
  }

#pragma unroll
  for (int i = 0; i < 4; ++i) {
#pragma unroll
    for (int r = 0; r < 4; ++r) {
      int R = m0 + wr * 64 + i * 16 + qd * 4 + r;
#pragma unroll
      for (int j = 0; j < 4; ++j) {
        int e = n0 + wc * 64 + j * 16 + lm;
        out[(size_t)R * 1024 + e] = acc[i][j][r] + bo[e];
      }
    }
  }
}

// ---------------- launch ----------------
extern "C" void kernel_launch(void* const* d_in, const int* in_sizes, int n_in,
                              void* d_out, int out_size, void* d_ws, size_t ws_size,
                              hipStream_t stream) {
  const float* x  = (const float*)d_in[0];
  const float* wq = (const float*)d_in[1];
  const float* bq = (const float*)d_in[2];
  const float* wk = (const float*)d_in[3];
  const float* bk = (const float*)d_in[4];
  const float* wv = (const float*)d_in[5];
  const float* bv = (const float*)d_in[6];
  const float* wo = (const float*)d_in[7];
  const float* bo = (const float*)d_in[8];
  float* out = (float*)d_out;

  char* ws = (char*)d_ws;
  u16* xb  = (u16*)(ws + 0);            // 33,554,432 B
  u16* wqh = (u16*)(ws + 33554432);     //  2,097,152 B each
  u16* wkh = (u16*)(ws + 35651584);
  u16* wvh = (u16*)(ws + 37748736);
  u16* woh = (u16*)(ws + 39845888);
  u16* Qfb = (u16*)(ws + 41943040);     // 33,554,432 B  [b][h][m][j] (pre-scaled)
  u16* Kfb = (u16*)(ws + 75497472);     // 33,554,432 B  [b][h][m][j]
  u16* Vtb = (u16*)(ws + 109051904);    // 33,554,432 B  [b][h][j][m]
  u16* Ofb = (u16*)(ws + 142606336);    // 33,554,432 B  [b][n][f]

  cvt_f32_f16<<<4096, 256, 0, stream>>>(x, xb, 16777216 / 4);
  Ptr8 p { wq, wk, wv, wo, wqh, wkh, wvh, woh };
  cvt4_f32_f16<<<dim3(256, 4), 256, 0, stream>>>(p, 1048576 / 4);

  proj_qkv<<<dim3(64, 8, 3), 512, 0, stream>>>(xb, wqh, wkh, wvh, bq, bk, bv,
                                               Qfb, Kfb, Vtb);
  attn_kernel<<<1024, 512, 0, stream>>>(Qfb, Kfb, Vtb, Ofb);
  out_gemm<<<dim3(64, 8), 512, 0, stream>>>(Ofb, woh, bo, out);
}